// Round 4
// baseline (244.941 us; speedup 1.0000x reference)
//
#include <hip/hip_runtime.h>
#include <stdint.h>

#define NN 65536
#define BB 64
#define TPB 256

// ---------------- fused geometry: 16 blocks/batch, 4096 pts/block, 16/thread
#define BPB 16
#define GRID_BLKS (BB * BPB)   // 1024 = 4 blocks/CU * 256 CU (forced by launch_bounds)
#define PPB 4096
#define LPT 16

// ---------------- fallback (proven baseline) geometry
#define FBPB 32
#define FGRID (BB * FBPB)      // 2048
#define FPPB 2048
#define FLPT 8
#define GBPB 16
#define GGRID (BB * GBPB)      // 1024
#define GLPT 16

// Exact-fp32 squared distance, matching numpy's ((dx*dx + dy*dy) + dz*dz)
// with no FMA contraction (rn intrinsics are never fused).
__device__ __forceinline__ float sqdist(float x, float y, float z,
                                        float cx, float cy, float cz) {
    float dx = __fsub_rn(x, cx);
    float dy = __fsub_rn(y, cy);
    float dz = __fsub_rn(z, cz);
    return __fadd_rn(__fadd_rn(__fmul_rn(dx, dx), __fmul_rn(dy, dy)),
                     __fmul_rn(dz, dz));
}

// Packed argmax key: (fp32 bits << 32) | (0xFFFFFFFF - index).
// Distances >= 0 so fp32 bit order == value order; ~index makes u64-max
// prefer the SMALLEST index on value ties (np.argmax semantics).
__device__ __forceinline__ unsigned long long pack_key(float v, int i) {
    return ((unsigned long long)__float_as_uint(v) << 32) |
           (unsigned long long)(0xFFFFFFFFu - (unsigned)i);
}

__device__ __forceinline__ int key_idx(unsigned long long key) {
    return (int)(0xFFFFFFFFu - (unsigned)(key & 0xFFFFFFFFu));
}

// ---- per-batch sense-reversing barrier, cache-maintenance-minimal ----
// Round-3 version spun on an ACQUIRE load (buffer_inv per poll!) and ran
// __threadfence() in every thread: a device-wide L2-invalidate storm that
// made the kernel stall-bound (VALUBusy 1.9%). New protocol:
//   data:    plain stores before / plain loads after (no per-access atomics)
//   arrive:  tid0 ACQ_REL fetch_add  (release half: one L2 writeback/block;
//            acquire half covers the closer's subsequent reads)
//   spin:    RELAXED load + s_sleep   (no cache maintenance at all)
//   wake:    one explicit agent ACQUIRE fence (one L1/L2 invalidate/block)
// Release-sequence chain through cnt->gen gives happens-before for the
// plain data accesses; 'g' is read before the RMW (pinned by its release
// half), so the sense logic is identical to the version that passed.
__device__ __forceinline__ void batch_barrier(unsigned* cnt, unsigned* gen) {
    __syncthreads();   // compiler drains vmcnt: all block stores are in cache
    if (threadIdx.x == 0) {
        unsigned g = __hip_atomic_load(gen, __ATOMIC_RELAXED,
                                       __HIP_MEMORY_SCOPE_AGENT);
        unsigned a = __hip_atomic_fetch_add(cnt, 1u, __ATOMIC_ACQ_REL,
                                            __HIP_MEMORY_SCOPE_AGENT) + 1u;
        if (a == (unsigned)BPB) {
            __hip_atomic_store(cnt, 0u, __ATOMIC_RELAXED,
                               __HIP_MEMORY_SCOPE_AGENT);
            __hip_atomic_store(gen, g + 1u, __ATOMIC_RELEASE,
                               __HIP_MEMORY_SCOPE_AGENT);
        } else {
            while (__hip_atomic_load(gen, __ATOMIC_RELAXED,
                                     __HIP_MEMORY_SCOPE_AGENT) == g)
                __builtin_amdgcn_s_sleep(4);
            __builtin_amdgcn_fence(__ATOMIC_ACQUIRE, "agent");
        }
    }
    __syncthreads();
}

__global__ void init_barrier(unsigned* bar) {
    const int t = threadIdx.x;   // 64 threads, one 128B line each
    bar[t * 32 + 0] = 0u;
    bar[t * 32 + 1] = 0u;
}

// =====================================================================
// Fused kernel: FPS (3 per-batch syncs) + mask + compaction/gather, with
// all 16 points/thread xyz held in VGPRs across the whole computation.
// =====================================================================
__global__ __launch_bounds__(TPB, 4) void fused_kernel(
        const float* __restrict__ pts,
        unsigned long long* __restrict__ partKey,
        uint64_t* __restrict__ masks,
        float* __restrict__ out,
        unsigned* __restrict__ bar) {
    const int gb = blockIdx.x;
    const int b = gb >> 4, blk = gb & 15;
    const int tid = threadIdx.x;
    const int lane = tid & 63, wid = tid >> 6;
    const float* base = pts + (size_t)b * NN * 6;
    unsigned* bcnt = bar + b * 32;
    unsigned* bgen = bar + b * 32 + 1;

    __shared__ unsigned long long s_k[4];
    __shared__ float s_c[3];
    __shared__ uint64_t s_m[1024];
    __shared__ int s_pre[1024];
    __shared__ int s_ws[4], s_wo[4];
    __shared__ int s_nv;

    // ---- load xyz ONCE into registers (48 VGPRs) ----
    // Round-3 profile showed VGPR_Count=64: the compiler rematerialized these
    // loads each FPS pass (pts is const __restrict__, so re-loading is legal).
    // The empty asm breaks the value<-load link and forces true residency.
    float px[LPT], py[LPT], pz[LPT], md[LPT];
    #pragma unroll
    for (int l = 0; l < LPT; ++l) {
        const int p = blk * PPB + l * TPB + tid;    // coalesced across lanes
        const float* q = base + (size_t)p * 6;
        float2 xy = *(const float2*)q;              // p*24 is 8B-aligned
        px[l] = xy.x; py[l] = xy.y; pz[l] = q[2];
        asm volatile("" : "+v"(px[l]), "+v"(py[l]), "+v"(pz[l]));
    }

    // center 0 = point 0 (pointnet2 convention)
    float cx = base[0], cy = base[1], cz = base[2];
    #pragma unroll
    for (int l = 0; l < LPT; ++l)
        md[l] = sqdist(px[l], py[l], pz[l], cx, cy, cz);

    // ---- FPS: centers 1..3 via per-batch argmax of md ----
    // Incremental fminf chain == sequential jnp.minimum chain bitwise.
    for (int k = 0; k < 3; ++k) {
        float bestv = -1.0f; int besti = 0x7fffffff;
        #pragma unroll
        for (int l = 0; l < LPT; ++l) {
            if (md[l] > bestv) { bestv = md[l]; besti = blk * PPB + l * TPB + tid; }
        }   // ascending index order -> strict '>' keeps earliest on ties
        unsigned long long key = pack_key(bestv, besti);
        #pragma unroll
        for (int off = 32; off > 0; off >>= 1) {
            unsigned long long ok = __shfl_down(key, off, 64);
            if (ok > key) key = ok;
        }
        if (lane == 0) s_k[wid] = key;
        __syncthreads();
        if (tid == 0) {
            unsigned long long bk = s_k[0];
            #pragma unroll
            for (int w = 1; w < 4; ++w) bk = (s_k[w] > bk) ? s_k[w] : bk;
            partKey[k * GRID_BLKS + gb] = bk;       // plain store; barrier orders it
        }
        batch_barrier(bcnt, bgen);

        // one thread reduces the batch's 16 partials -> center coords to LDS
        if (tid == 0) {
            const unsigned long long* s = partKey + k * GRID_BLKS + b * BPB;
            unsigned long long bk = s[0];           // plain loads (post-acquire)
            #pragma unroll
            for (int w = 1; w < BPB; ++w) bk = (s[w] > bk) ? s[w] : bk;
            const float* cp = base + (size_t)key_idx(bk) * 6;
            s_c[0] = cp[0]; s_c[1] = cp[1]; s_c[2] = cp[2];
        }
        __syncthreads();
        cx = s_c[0]; cy = s_c[1]; cz = s_c[2];
        #pragma unroll
        for (int l = 0; l < LPT; ++l)
            md[l] = fminf(md[l], sqdist(px[l], py[l], pz[l], cx, cy, cz));
    }

    // ---- keep bits -> ballot -> mask words ----
    uint64_t* mb = masks + (size_t)b * 1024;
    #pragma unroll
    for (int l = 0; l < LPT; ++l) {
        // sqrt_rn is monotone & correctly rounded: sqrt(min d^2)==min(norm)
        int keep = (__fsqrt_rn(md[l]) >= 0.2f) ? 1 : 0;
        uint64_t m = __ballot(keep);                // bit L == point p0 + L
        if (lane == 0) mb[blk * 64 + l * 4 + wid] = m;   // plain store
    }
    batch_barrier(bcnt, bgen);

    // ---- fused compaction + cyclic gather ----
    uint64_t w[4];
    int cnt = 0;
    #pragma unroll
    for (int kk = 0; kk < 4; ++kk) {
        w[kk] = mb[tid * 4 + kk];                   // plain coalesced loads
        s_m[tid * 4 + kk] = w[kk];
        cnt += __popcll(w[kk]);
    }
    // block exclusive scan of per-thread counts (thread order == word order)
    int incl = cnt;
    #pragma unroll
    for (int off = 1; off < 64; off <<= 1) {
        int v = __shfl_up(incl, off, 64);
        if (lane >= off) incl += v;
    }
    if (lane == 63) s_ws[wid] = incl;
    __syncthreads();
    if (tid == 0) {
        int run = 0;
        #pragma unroll
        for (int q = 0; q < 4; ++q) { s_wo[q] = run; run += s_ws[q]; }
        s_nv = run;
    }
    __syncthreads();
    int run = s_wo[wid] + incl - cnt;               // exclusive offset, word 4t
    #pragma unroll
    for (int kk = 0; kk < 4; ++kk) {
        s_pre[tid * 4 + kk] = run;
        run += __popcll(w[kk]);
    }
    __syncthreads();

    const int nv = s_nv;
    float* ob = out + (size_t)b * NN * 6;

    if (nv <= 0) {
        float2 zz = make_float2(0.f, 0.f);
        #pragma unroll
        for (int l = 0; l < LPT; ++l) {
            int j = blk * PPB + l * TPB + tid;
            float2* o = (float2*)(ob + (size_t)j * 6);
            o[0] = zz; o[1] = zz; o[2] = zz;
        }
        return;
    }

    #pragma unroll
    for (int l = 0; l < LPT; ++l) {
        int j = blk * PPB + l * TPB + tid;          // coalesced across lanes
        int jj = (int)((unsigned)j % (unsigned)nv); // rank of source point
        // largest word wd with s_pre[wd] <= jj  (s_pre[0]==0 <= jj always)
        int wd = 0;
        #pragma unroll
        for (int s = 512; s > 0; s >>= 1) {
            int cand = wd + s;
            if (cand < 1024 && s_pre[cand] <= jj) wd = cand;
        }
        int r = jj - s_pre[wd];
        uint64_t m = s_m[wd];
        // select r-th (0-based, from LSB) set bit of m
        int bit = 0;
        int c = __popcll(m & 0xFFFFFFFFull);
        if (r >= c) { r -= c; m >>= 32; bit += 32; }
        c = __popcll(m & 0xFFFFull);
        if (r >= c) { r -= c; m >>= 16; bit += 16; }
        c = __popcll(m & 0xFFull);
        if (r >= c) { r -= c; m >>= 8; bit += 8; }
        c = __popcll(m & 0xFull);
        if (r >= c) { r -= c; m >>= 4; bit += 4; }
        c = __popcll(m & 0x3ull);
        if (r >= c) { r -= c; m >>= 2; bit += 2; }
        if (r >= (int)(m & 1ull)) { bit += 1; }
        int src = wd * 64 + bit;
        const float2* p = (const float2*)(base + (size_t)src * 6);
        float2* o = (float2*)(ob + (size_t)j * 6);
        float2 r0 = p[0], r1 = p[1], r2 = p[2];
        o[0] = r0; o[1] = r1; o[2] = r2;
    }
}

// =====================================================================
// Fallback: the proven 5-kernel pipeline (baseline, 247 us), verbatim.
// =====================================================================
__device__ __forceinline__ int reduce_part(const unsigned long long* partKey,
                                           int a, int b) {
    const unsigned long long* s = partKey + a * FGRID + b * FBPB;
    unsigned long long bk = s[0];
    #pragma unroll
    for (int w = 1; w < FBPB; ++w) bk = (s[w] > bk) ? s[w] : bk;
    return key_idx(bk);
}

template<int NC>
__global__ __launch_bounds__(TPB) void fps_pass(
        const float* __restrict__ pts, unsigned long long* partKey) {
    const int gb = blockIdx.x;
    const int b = gb >> 5, blk = gb & 31;
    const int tid = threadIdx.x;
    const int lane = tid & 63, wid = tid >> 6;
    const float* base = pts + (size_t)b * NN * 6;

    float cx[NC], cy[NC], cz[NC];
    cx[0] = base[0]; cy[0] = base[1]; cz[0] = base[2];
    #pragma unroll
    for (int k = 1; k < NC; ++k) {
        int idx = reduce_part(partKey, k - 1, b);
        const float* p = base + (size_t)idx * 6;
        cx[k] = p[0]; cy[k] = p[1]; cz[k] = p[2];
    }

    float bestv = -1.0f; int besti = 0x7fffffff;
    #pragma unroll
    for (int l = 0; l < FLPT; ++l) {
        const int p = blk * FPPB + l * TPB + tid;
        const float* q = base + (size_t)p * 6;
        float2 xy = *(const float2*)q;
        float  zz = q[2];
        float d = sqdist(xy.x, xy.y, zz, cx[0], cy[0], cz[0]);
        #pragma unroll
        for (int k = 1; k < NC; ++k)
            d = fminf(d, sqdist(xy.x, xy.y, zz, cx[k], cy[k], cz[k]));
        if (d > bestv) { bestv = d; besti = p; }
    }
    unsigned long long key = pack_key(bestv, besti);
    #pragma unroll
    for (int off = 32; off > 0; off >>= 1) {
        unsigned long long ok = __shfl_down(key, off, 64);
        if (ok > key) key = ok;
    }
    __shared__ unsigned long long s_k[4];
    if (lane == 0) s_k[wid] = key;
    __syncthreads();
    if (tid == 0) {
        unsigned long long bk = s_k[0];
        #pragma unroll
        for (int w = 1; w < 4; ++w) bk = (s_k[w] > bk) ? s_k[w] : bk;
        partKey[(NC - 1) * FGRID + gb] = bk;
    }
}

__global__ __launch_bounds__(TPB) void fps_final(
        const float* __restrict__ pts,
        const unsigned long long* __restrict__ partKey,
        uint64_t* __restrict__ masks) {
    const int gb = blockIdx.x;
    const int b = gb >> 5, blk = gb & 31;
    const int tid = threadIdx.x;
    const int lane = tid & 63, wid = tid >> 6;
    const float* base = pts + (size_t)b * NN * 6;

    float cx[4], cy[4], cz[4];
    cx[0] = base[0]; cy[0] = base[1]; cz[0] = base[2];
    #pragma unroll
    for (int k = 1; k < 4; ++k) {
        int idx = reduce_part(partKey, k - 1, b);
        const float* p = base + (size_t)idx * 6;
        cx[k] = p[0]; cy[k] = p[1]; cz[k] = p[2];
    }
    uint64_t* mb = masks + (size_t)b * 1024;

    #pragma unroll
    for (int l = 0; l < FLPT; ++l) {
        const int p = blk * FPPB + l * TPB + tid;
        const float* q = base + (size_t)p * 6;
        float2 xy = *(const float2*)q;
        float  zz = q[2];
        float d = sqdist(xy.x, xy.y, zz, cx[0], cy[0], cz[0]);
        #pragma unroll
        for (int k = 1; k < 4; ++k)
            d = fminf(d, sqdist(xy.x, xy.y, zz, cx[k], cy[k], cz[k]));
        int keep = (__fsqrt_rn(d) >= 0.2f) ? 1 : 0;
        uint64_t m = __ballot(keep);
        if (lane == 0) mb[blk * 32 + l * 4 + wid] = m;
    }
}

__global__ __launch_bounds__(TPB) void gather_kernel(
        const float* __restrict__ pts, const uint64_t* __restrict__ masks,
        float* __restrict__ out) {
    const int gb = blockIdx.x;
    const int b = gb >> 4, blk = gb & 15;
    const int tid = threadIdx.x;
    const int lane = tid & 63, wid = tid >> 6;
    __shared__ uint64_t s_m[1024];
    __shared__ int s_pre[1024];
    __shared__ int s_ws[4], s_wo[4];
    __shared__ int s_nv;

    const uint64_t* mb = masks + (size_t)b * 1024;
    uint64_t w[4];
    int cnt = 0;
    #pragma unroll
    for (int k = 0; k < 4; ++k) {
        w[k] = mb[tid * 4 + k];
        s_m[tid * 4 + k] = w[k];
        cnt += __popcll(w[k]);
    }
    int incl = cnt;
    #pragma unroll
    for (int off = 1; off < 64; off <<= 1) {
        int v = __shfl_up(incl, off, 64);
        if (lane >= off) incl += v;
    }
    if (lane == 63) s_ws[wid] = incl;
    __syncthreads();
    if (tid == 0) {
        int run = 0;
        #pragma unroll
        for (int q = 0; q < 4; ++q) { s_wo[q] = run; run += s_ws[q]; }
        s_nv = run;
    }
    __syncthreads();
    int run = s_wo[wid] + incl - cnt;
    #pragma unroll
    for (int k = 0; k < 4; ++k) {
        s_pre[tid * 4 + k] = run;
        run += __popcll(w[k]);
    }
    __syncthreads();

    const int nv = s_nv;
    const float* baseP = pts + (size_t)b * NN * 6;
    float* ob = out + (size_t)b * NN * 6;

    if (nv <= 0) {
        float2 zz = make_float2(0.f, 0.f);
        #pragma unroll
        for (int l = 0; l < GLPT; ++l) {
            int j = blk * 4096 + l * TPB + tid;
            float2* o = (float2*)(ob + (size_t)j * 6);
            o[0] = zz; o[1] = zz; o[2] = zz;
        }
        return;
    }

    #pragma unroll
    for (int l = 0; l < GLPT; ++l) {
        int j = blk * 4096 + l * TPB + tid;
        int jj = (int)((unsigned)j % (unsigned)nv);
        int wd = 0;
        #pragma unroll
        for (int s = 512; s > 0; s >>= 1) {
            int cand = wd + s;
            if (cand < 1024 && s_pre[cand] <= jj) wd = cand;
        }
        int r = jj - s_pre[wd];
        uint64_t m = s_m[wd];
        int bit = 0;
        int c = __popcll(m & 0xFFFFFFFFull);
        if (r >= c) { r -= c; m >>= 32; bit += 32; }
        c = __popcll(m & 0xFFFFull);
        if (r >= c) { r -= c; m >>= 16; bit += 16; }
        c = __popcll(m & 0xFFull);
        if (r >= c) { r -= c; m >>= 8; bit += 8; }
        c = __popcll(m & 0xFull);
        if (r >= c) { r -= c; m >>= 4; bit += 4; }
        c = __popcll(m & 0x3ull);
        if (r >= c) { r -= c; m >>= 2; bit += 2; }
        if (r >= (int)(m & 1ull)) { bit += 1; }
        int src = wd * 64 + bit;
        const float2* p = (const float2*)(baseP + (size_t)src * 6);
        float2* o = (float2*)(ob + (size_t)j * 6);
        float2 r0 = p[0], r1 = p[1], r2 = p[2];
        o[0] = r0; o[1] = r1; o[2] = r2;
    }
}

extern "C" void kernel_launch(void* const* d_in, const int* in_sizes, int n_in,
                              void* d_out, int out_size, void* d_ws, size_t ws_size,
                              hipStream_t stream) {
    const float* pts = (const float*)d_in[0];
    float* out = (float*)d_out;

    // workspace layout (no memset needed for data; barrier zeroed by init kernel)
    unsigned long long* partKey = (unsigned long long*)d_ws;        // fused 24KB / fallback 48KB
    unsigned* bar = (unsigned*)((char*)d_ws + (48 << 10));          // 8KB: 64 lines x 128B
    uint64_t* masks = (uint64_t*)((char*)d_ws + (64 << 10));        // 512KB

    // One-time residency gate (pure host queries; capture-safe).
    static int fused_ok = -1;
    if (fused_ok < 0) {
        int dev = 0;
        (void)hipGetDevice(&dev);
        int ncu = 0, nb = 0;
        hipError_t e1 = hipDeviceGetAttribute(&ncu, hipDeviceAttributeMultiprocessorCount, dev);
        hipError_t e2 = hipOccupancyMaxActiveBlocksPerMultiprocessor(
            &nb, (const void*)fused_kernel, TPB, 0);
        fused_ok = (e1 == hipSuccess && e2 == hipSuccess &&
                    (long)nb * (long)ncu >= (long)GRID_BLKS) ? 1 : 0;
    }

    if (fused_ok) {
        init_barrier<<<1, 64, 0, stream>>>(bar);
        fused_kernel<<<GRID_BLKS, TPB, 0, stream>>>(pts, partKey, masks, out, bar);
    } else {
        fps_pass<1><<<FGRID, TPB, 0, stream>>>(pts, partKey);
        fps_pass<2><<<FGRID, TPB, 0, stream>>>(pts, partKey);
        fps_pass<3><<<FGRID, TPB, 0, stream>>>(pts, partKey);
        fps_final<<<FGRID, TPB, 0, stream>>>(pts, partKey, masks);
        gather_kernel<<<GGRID, TPB, 0, stream>>>(pts, masks, out);
    }
}